// Round 1
// baseline (315.770 us; speedup 1.0000x reference)
//
#include <hip/hip_runtime.h>
#include <stdint.h>

#define S_LEN 2048
#define DMODEL 2048
#define NQH 16
#define NKVH 4
#define HDK 128

typedef __bf16 bf16x8 __attribute__((ext_vector_type(8)));
typedef float f32x4 __attribute__((ext_vector_type(4)));

__device__ __forceinline__ void async16(const void* g, void* l) {
  __builtin_amdgcn_global_load_lds((const __attribute__((address_space(1))) void*)g,
                                   (__attribute__((address_space(3))) void*)l,
                                   16, 0, 0);
}

__device__ __forceinline__ f32x4 mfma16(bf16x8 a, bf16x8 b, f32x4 c) {
  return __builtin_amdgcn_mfma_f32_16x16x32_bf16(a, b, c, 0, 0, 0);
}

// ---------------- fp32 -> bf16 conversion ----------------
__global__ __launch_bounds__(256) void cvt_bf16(const float* __restrict__ in,
                                                __bf16* __restrict__ out, int n) {
  int i = (blockIdx.x * 256 + threadIdx.x) * 8;
  if (i >= n) return;
  const float4* p = (const float4*)(in + i);
  float4 a = p[0], b = p[1];
  bf16x8 o;
  o[0] = (__bf16)a.x; o[1] = (__bf16)a.y; o[2] = (__bf16)a.z; o[3] = (__bf16)a.w;
  o[4] = (__bf16)b.x; o[5] = (__bf16)b.y; o[6] = (__bf16)b.z; o[7] = (__bf16)b.w;
  *(bf16x8*)(out + i) = o;
}

// ---------------- GEMM: C[m,n] = sum_k A[m,k]*B[n,k]  (both row-major, K contig) ----------------
// 128x128 tile, BK=64, 4 waves, global_load_lds(16B) + XOR-swizzled LDS.
// Fused dual-output: n0 < Nsplit -> (Ba,Ca) else (Bb,Cb). Pass Nsplit=Ntot for single.
template <bool F32OUT>
__global__ __launch_bounds__(256) void gemm_bt(const __bf16* __restrict__ A,
                                               const __bf16* __restrict__ Ba,
                                               const __bf16* __restrict__ Bb,
                                               void* __restrict__ Ca,
                                               void* __restrict__ Cb,
                                               int M, int Ntot, int Nsplit, int K) {
  int nbn = Ntot >> 7;
  int bx = blockIdx.x;
  int m0 = (bx / nbn) << 7;
  int n0g = (bx % nbn) << 7;
  const __bf16* B;
  void* C;
  int n0, Nc;
  if (n0g < Nsplit) { B = Ba; C = Ca; n0 = n0g; Nc = Nsplit; }
  else              { B = Bb; C = Cb; n0 = n0g - Nsplit; Nc = Ntot - Nsplit; }

  __shared__ __align__(16) uint8_t As[16384]; // [128][64] bf16, XOR-swizzled
  __shared__ __align__(16) uint8_t Bs[16384];

  int t = threadIdx.x, lane = t & 63, w = t >> 6;
  int wr = w >> 1, wc = w & 1;
  f32x4 acc[4][4] = {};

  for (int k0 = 0; k0 < K; k0 += 64) {
#pragma unroll
    for (int i = 0; i < 4; ++i) {
      int c = (i << 8) + t;
      int row = c >> 3;
      int colb = ((c & 7) << 4) ^ ((row & 7) << 4);
      async16((const uint8_t*)(A + (size_t)(m0 + row) * K + k0) + colb, As + c * 16);
      async16((const uint8_t*)(B + (size_t)(n0 + row) * K + k0) + colb, Bs + c * 16);
    }
    __syncthreads();
#pragma unroll
    for (int ks = 0; ks < 2; ++ks) {
      bf16x8 af[4], bfr[4];
#pragma unroll
      for (int m = 0; m < 4; ++m) {
        int row = wr * 64 + m * 16 + (lane & 15);
        int colb = ((ks << 6) + ((lane >> 4) << 4)) ^ ((row & 7) << 4);
        af[m] = *(const bf16x8*)(As + row * 128 + colb);
      }
#pragma unroll
      for (int n = 0; n < 4; ++n) {
        int row = wc * 64 + n * 16 + (lane & 15);
        int colb = ((ks << 6) + ((lane >> 4) << 4)) ^ ((row & 7) << 4);
        bfr[n] = *(const bf16x8*)(Bs + row * 128 + colb);
      }
#pragma unroll
      for (int m = 0; m < 4; ++m)
#pragma unroll
        for (int n = 0; n < 4; ++n)
          acc[m][n] = mfma16(af[m], bfr[n], acc[m][n]);
    }
    __syncthreads();
  }
  // epilogue: C/D layout col = lane&15, row = (lane>>4)*4 + j
#pragma unroll
  for (int m = 0; m < 4; ++m)
#pragma unroll
    for (int n = 0; n < 4; ++n)
#pragma unroll
      for (int j = 0; j < 4; ++j) {
        int mg = m0 + wr * 64 + m * 16 + ((lane >> 4) << 2) + j;
        int ng = n0 + wc * 64 + n * 16 + (lane & 15);
        float v = acc[m][n][j];
        if (F32OUT) ((float*)C)[(size_t)mg * Nc + ng] = v;
        else        ((__bf16*)C)[(size_t)mg * Nc + ng] = (__bf16)v;
      }
}

// ---------------- V transpose: (B*S, 512) -> Vt[(b*4+kvh)*128 + d][s] ----------------
__global__ __launch_bounds__(256) void transpose_v(const __bf16* __restrict__ V,
                                                   __bf16* __restrict__ Vt) {
  int bid = blockIdx.x;
  int dt = bid & 1, st = (bid >> 1) & 31, kvh = (bid >> 6) & 3, b = bid >> 8;
  __shared__ __align__(16) __bf16 tile[64][72];
  int t = threadIdx.x;
#pragma unroll
  for (int i = 0; i < 2; ++i) {
    int c = (i << 8) + t;
    int sr = c >> 3, cb = (c & 7) << 3;
    bf16x8 v = *(const bf16x8*)(V + (size_t)(b * S_LEN + st * 64 + sr) * 512 +
                                kvh * HDK + dt * 64 + cb);
    *(bf16x8*)(&tile[sr][cb]) = v;
  }
  __syncthreads();
#pragma unroll
  for (int i = 0; i < 2; ++i) {
    int c = (i << 8) + t;
    int dr = c >> 3, sb = (c & 7) << 3;
    bf16x8 o;
#pragma unroll
    for (int j = 0; j < 8; ++j) o[j] = tile[sb + j][dr];
    *(bf16x8*)(Vt + (size_t)((b * NKVH + kvh) * HDK + dt * 64 + dr) * S_LEN +
               st * 64 + sb) = o;
  }
}

// ---------------- causal GQA flash attention ----------------
// Q:(B*S,2048) K:(B*S,512) Vt:((b*4+kvh)*128, S) -> Ctx:(B*S,2048), all bf16
__global__ __launch_bounds__(256) void attn(const __bf16* __restrict__ Q,
                                            const __bf16* __restrict__ Kx,
                                            const __bf16* __restrict__ Vt,
                                            __bf16* __restrict__ Ctx) {
  int bid = blockIdx.x;
  int qt = 31 - (bid & 31);  // longest blocks first
  int h = (bid >> 5) & 15;
  int b = bid >> 9;
  int kvh = h >> 2;
  int q0 = qt << 6;
  int t = threadIdx.x, lane = t & 63, w = t >> 6;

  __shared__ __align__(16) uint8_t Qs[16384];  // [64][128] bf16, swizzled
  __shared__ __align__(16) uint8_t Ks[16384];  // [64][128] bf16, swizzled
  __shared__ __align__(16) uint8_t Vs[16384];  // [128][64] bf16 (d-major), swizzled
  __shared__ __align__(16) __bf16 Ps[4][16][72];  // per-wave P, padded

  // stage Q tile
#pragma unroll
  for (int i = 0; i < 4; ++i) {
    int c = (i << 8) + t;
    int row = c >> 4;
    int colb = ((c & 15) << 4) ^ ((row & 7) << 4);
    async16((const uint8_t*)(Q + (size_t)(b * S_LEN + q0 + row) * DMODEL + h * HDK) + colb,
            Qs + c * 16);
  }
  __syncthreads();
  bf16x8 qf[4];
#pragma unroll
  for (int dc = 0; dc < 4; ++dc) {
    int row = w * 16 + (lane & 15);
    int colb = ((dc << 6) + ((lane >> 4) << 4)) ^ ((row & 7) << 4);
    qf[dc] = *(const bf16x8*)(Qs + row * 256 + colb);
  }

  const float NEG = -3.0e38f;
  const float SC = 0.08838834764831845f;  // 1/sqrt(128)
  float m_run[4] = {NEG, NEG, NEG, NEG};
  float l_run[4] = {0.f, 0.f, 0.f, 0.f};
  f32x4 acc_o[8] = {};

  for (int kt = 0; kt <= qt; ++kt) {
    int k0 = kt << 6;
#pragma unroll
    for (int i = 0; i < 4; ++i) {
      int c = (i << 8) + t;
      int krow = c >> 4;
      int kcolb = ((c & 15) << 4) ^ ((krow & 7) << 4);
      async16((const uint8_t*)(Kx + (size_t)(b * S_LEN + k0 + krow) * 512 + kvh * HDK) + kcolb,
              Ks + c * 16);
      int vrow = c >> 3;
      int vcolb = ((c & 7) << 4) ^ ((vrow & 7) << 4);
      async16((const uint8_t*)(Vt + (size_t)((b * NKVH + kvh) * HDK + vrow) * S_LEN + k0) + vcolb,
              Vs + c * 16);
    }
    __syncthreads();

    // S = Q K^T  (16q x 64k per wave)
    f32x4 sc[4] = {};
#pragma unroll
    for (int kf = 0; kf < 4; ++kf)
#pragma unroll
      for (int dc = 0; dc < 4; ++dc) {
        int row = kf * 16 + (lane & 15);
        int colb = ((dc << 6) + ((lane >> 4) << 4)) ^ ((row & 7) << 4);
        bf16x8 kfr = *(const bf16x8*)(Ks + row * 256 + colb);
        sc[kf] = mfma16(qf[dc], kfr, sc[kf]);
      }

    if (kt == qt) {
#pragma unroll
      for (int kf = 0; kf < 4; ++kf)
#pragma unroll
        for (int j = 0; j < 4; ++j) {
          int key = kf * 16 + (lane & 15);
          int qq = w * 16 + ((lane >> 4) << 2) + j;
          sc[kf][j] = (key <= qq) ? sc[kf][j] * SC : NEG;
        }
    } else {
#pragma unroll
      for (int kf = 0; kf < 4; ++kf)
#pragma unroll
        for (int j = 0; j < 4; ++j) sc[kf][j] *= SC;
    }

    float mx[4];
#pragma unroll
    for (int j = 0; j < 4; ++j)
      mx[j] = fmaxf(fmaxf(sc[0][j], sc[1][j]), fmaxf(sc[2][j], sc[3][j]));
#pragma unroll
    for (int off = 1; off < 16; off <<= 1)
#pragma unroll
      for (int j = 0; j < 4; ++j) mx[j] = fmaxf(mx[j], __shfl_xor(mx[j], off, 64));

    float al[4], rs[4];
#pragma unroll
    for (int j = 0; j < 4; ++j) {
      float mn = fmaxf(m_run[j], mx[j]);
      al[j] = __expf(m_run[j] - mn);
      m_run[j] = mn;
      rs[j] = 0.f;
    }
#pragma unroll
    for (int kf = 0; kf < 4; ++kf)
#pragma unroll
      for (int j = 0; j < 4; ++j) {
        float p = __expf(sc[kf][j] - m_run[j]);
        sc[kf][j] = p;
        rs[j] += p;
      }
#pragma unroll
    for (int off = 1; off < 16; off <<= 1)
#pragma unroll
      for (int j = 0; j < 4; ++j) rs[j] += __shfl_xor(rs[j], off, 64);
#pragma unroll
    for (int j = 0; j < 4; ++j) l_run[j] = l_run[j] * al[j] + rs[j];
#pragma unroll
    for (int nf = 0; nf < 8; ++nf)
#pragma unroll
      for (int j = 0; j < 4; ++j) acc_o[nf][j] *= al[j];

    // P -> LDS (C-layout scatter), read back as MFMA A-frags
#pragma unroll
    for (int kf = 0; kf < 4; ++kf)
#pragma unroll
      for (int j = 0; j < 4; ++j)
        Ps[w][((lane >> 4) << 2) + j][kf * 16 + (lane & 15)] = (__bf16)sc[kf][j];
    bf16x8 pa[2];
#pragma unroll
    for (int kc = 0; kc < 2; ++kc)
      pa[kc] = *(const bf16x8*)(&Ps[w][lane & 15][kc * 32 + ((lane >> 4) << 3)]);

    // O += P V
#pragma unroll
    for (int nf = 0; nf < 8; ++nf)
#pragma unroll
      for (int kc = 0; kc < 2; ++kc) {
        int row = nf * 16 + (lane & 15);
        int colb = ((kc << 6) + ((lane >> 4) << 4)) ^ ((row & 7) << 4);
        bf16x8 vfr = *(const bf16x8*)(Vs + row * 128 + colb);
        acc_o[nf] = mfma16(pa[kc], vfr, acc_o[nf]);
      }
    __syncthreads();
  }

  float inv[4];
#pragma unroll
  for (int j = 0; j < 4; ++j) inv[j] = 1.f / l_run[j];
#pragma unroll
  for (int nf = 0; nf < 8; ++nf)
#pragma unroll
    for (int j = 0; j < 4; ++j) {
      size_t idx = (size_t)(b * S_LEN + q0 + w * 16 + ((lane >> 4) << 2) + j) * DMODEL +
                   h * HDK + nf * 16 + (lane & 15);
      Ctx[idx] = (__bf16)(acc_o[nf][j] * inv[j]);
    }
}

// ---------------- launch ----------------
extern "C" void kernel_launch(void* const* d_in, const int* in_sizes, int n_in,
                              void* d_out, int out_size, void* d_ws, size_t ws_size,
                              hipStream_t stream) {
  const float* x  = (const float*)d_in[0];
  const float* Wq = (const float*)d_in[1];
  const float* Wk = (const float*)d_in[2];
  const float* Wv = (const float*)d_in[3];
  const float* Wo = (const float*)d_in[4];
  float* out = (float*)d_out;

  const size_t MB = 1024 * 1024;
  uint8_t* ws = (uint8_t*)d_ws;
  __bf16* xb  = (__bf16*)(ws + 0 * MB);   // 16 MB  (4096 x 2048)
  __bf16* Wqb = (__bf16*)(ws + 16 * MB);  //  8 MB  (2048 x 2048)
  __bf16* Wkb = (__bf16*)(ws + 24 * MB);  //  2 MB  (512 x 2048)
  __bf16* Wvb = (__bf16*)(ws + 26 * MB);  //  2 MB
  __bf16* Wob = (__bf16*)(ws + 28 * MB);  //  8 MB
  __bf16* Qb  = (__bf16*)(ws + 36 * MB);  // 16 MB  (4096 x 2048)
  __bf16* Kb  = (__bf16*)(ws + 52 * MB);  //  4 MB  (4096 x 512)
  __bf16* Vb  = (__bf16*)(ws + 56 * MB);  //  4 MB
  __bf16* Vtb = (__bf16*)(ws + 60 * MB);  //  4 MB  (1024 x 2048)
  __bf16* Ctx = (__bf16*)(ws + 64 * MB);  // 16 MB  (4096 x 2048)

  cvt_bf16<<<8388608 / 2048, 256, 0, stream>>>(x, xb, 8388608);
  cvt_bf16<<<4194304 / 2048, 256, 0, stream>>>(Wq, Wqb, 4194304);
  cvt_bf16<<<1048576 / 2048, 256, 0, stream>>>(Wk, Wkb, 1048576);
  cvt_bf16<<<1048576 / 2048, 256, 0, stream>>>(Wv, Wvb, 1048576);
  cvt_bf16<<<4194304 / 2048, 256, 0, stream>>>(Wo, Wob, 4194304);

  // Q projection: (4096x2048) x (2048x2048)^T
  gemm_bt<false><<<(4096 / 128) * (2048 / 128), 256, 0, stream>>>(
      xb, Wqb, Wqb, (void*)Qb, (void*)Qb, 4096, 2048, 2048, 2048);
  // K|V projections fused: N = 512+512
  gemm_bt<false><<<(4096 / 128) * (1024 / 128), 256, 0, stream>>>(
      xb, Wkb, Wvb, (void*)Kb, (void*)Vb, 4096, 1024, 512, 2048);

  transpose_v<<<512, 256, 0, stream>>>(Vb, Vtb);

  attn<<<2 * 16 * 32, 256, 0, stream>>>(Qb, Kb, Vtb, Ctx);

  // output projection: (4096x2048) x (2048x2048)^T -> fp32
  gemm_bt<true><<<(4096 / 128) * (2048 / 128), 256, 0, stream>>>(
      Ctx, Wob, Wob, (void*)out, (void*)out, 4096, 2048, 2048, 2048);
}

// Round 2
// 315.109 us; speedup vs baseline: 1.0021x; 1.0021x over previous
//
#include <hip/hip_runtime.h>
#include <stdint.h>

#define S_LEN 2048
#define DMODEL 2048
#define NQH 16
#define NKVH 4
#define HDK 128

typedef __bf16 bf16x8 __attribute__((ext_vector_type(8)));
typedef float f32x4 __attribute__((ext_vector_type(4)));

__device__ __forceinline__ void async16(const void* g, void* l) {
  __builtin_amdgcn_global_load_lds((const __attribute__((address_space(1))) void*)g,
                                   (__attribute__((address_space(3))) void*)l,
                                   16, 0, 0);
}

__device__ __forceinline__ f32x4 mfma16(bf16x8 a, bf16x8 b, f32x4 c) {
  return __builtin_amdgcn_mfma_f32_16x16x32_bf16(a, b, c, 0, 0, 0);
}

// ---------------- fp32 -> bf16 conversion ----------------
__global__ __launch_bounds__(256) void cvt_bf16(const float* __restrict__ in,
                                                __bf16* __restrict__ out, int n) {
  int i = (blockIdx.x * 256 + threadIdx.x) * 8;
  if (i >= n) return;
  const float4* p = (const float4*)(in + i);
  float4 a = p[0], b = p[1];
  bf16x8 o;
  o[0] = (__bf16)a.x; o[1] = (__bf16)a.y; o[2] = (__bf16)a.z; o[3] = (__bf16)a.w;
  o[4] = (__bf16)b.x; o[5] = (__bf16)b.y; o[6] = (__bf16)b.z; o[7] = (__bf16)b.w;
  *(bf16x8*)(out + i) = o;
}

// ---------------- GEMM: C[m,n] = sum_k A[m,k]*B[n,k]  (both row-major, K contig) ----------------
// 128x128 tile, BK=64, 4 waves, global_load_lds(16B) + XOR-swizzled LDS.
// Fused dual-output: n0 < Nsplit -> (Ba,Ca) else (Bb,Cb). Pass Nsplit=Ntot for single.
template <bool F32OUT>
__global__ __launch_bounds__(256) void gemm_bt(const __bf16* __restrict__ A,
                                               const __bf16* __restrict__ Ba,
                                               const __bf16* __restrict__ Bb,
                                               void* __restrict__ Ca,
                                               void* __restrict__ Cb,
                                               int M, int Ntot, int Nsplit, int K) {
  int nbn = Ntot >> 7;
  int bx = blockIdx.x;
  int m0 = (bx / nbn) << 7;
  int n0g = (bx % nbn) << 7;
  const __bf16* B;
  void* C;
  int n0, Nc;
  if (n0g < Nsplit) { B = Ba; C = Ca; n0 = n0g; Nc = Nsplit; }
  else              { B = Bb; C = Cb; n0 = n0g - Nsplit; Nc = Ntot - Nsplit; }

  __shared__ __align__(16) uint8_t As[16384]; // [128][64] bf16, XOR-swizzled
  __shared__ __align__(16) uint8_t Bs[16384];

  int t = threadIdx.x, lane = t & 63, w = t >> 6;
  int wr = w >> 1, wc = w & 1;
  f32x4 acc[4][4] = {};

  for (int k0 = 0; k0 < K; k0 += 64) {
#pragma unroll
    for (int i = 0; i < 4; ++i) {
      int c = (i << 8) + t;
      int row = c >> 3;
      int colb = ((c & 7) << 4) ^ ((row & 7) << 4);
      async16((const uint8_t*)(A + (size_t)(m0 + row) * K + k0) + colb, As + c * 16);
      async16((const uint8_t*)(B + (size_t)(n0 + row) * K + k0) + colb, Bs + c * 16);
    }
    __syncthreads();
#pragma unroll
    for (int ks = 0; ks < 2; ++ks) {
      bf16x8 af[4], bfr[4];
#pragma unroll
      for (int m = 0; m < 4; ++m) {
        int row = wr * 64 + m * 16 + (lane & 15);
        int colb = ((ks << 6) + ((lane >> 4) << 4)) ^ ((row & 7) << 4);
        af[m] = *(const bf16x8*)(As + row * 128 + colb);
      }
#pragma unroll
      for (int n = 0; n < 4; ++n) {
        int row = wc * 64 + n * 16 + (lane & 15);
        int colb = ((ks << 6) + ((lane >> 4) << 4)) ^ ((row & 7) << 4);
        bfr[n] = *(const bf16x8*)(Bs + row * 128 + colb);
      }
      __builtin_amdgcn_s_setprio(1);
#pragma unroll
      for (int m = 0; m < 4; ++m)
#pragma unroll
        for (int n = 0; n < 4; ++n)
          acc[m][n] = mfma16(af[m], bfr[n], acc[m][n]);
      __builtin_amdgcn_s_setprio(0);
    }
    __syncthreads();
  }
  // epilogue: C/D layout col = lane&15, row = (lane>>4)*4 + j
#pragma unroll
  for (int m = 0; m < 4; ++m)
#pragma unroll
    for (int n = 0; n < 4; ++n)
#pragma unroll
      for (int j = 0; j < 4; ++j) {
        int mg = m0 + wr * 64 + m * 16 + ((lane >> 4) << 2) + j;
        int ng = n0 + wc * 64 + n * 16 + (lane & 15);
        float v = acc[m][n][j];
        if (F32OUT) ((float*)C)[(size_t)mg * Nc + ng] = v;
        else        ((__bf16*)C)[(size_t)mg * Nc + ng] = (__bf16)v;
      }
}

// ---------------- V transpose: (B*S, 512) -> Vt[(b*4+kvh)*128 + d][s] ----------------
__global__ __launch_bounds__(256) void transpose_v(const __bf16* __restrict__ V,
                                                   __bf16* __restrict__ Vt) {
  int bid = blockIdx.x;
  int dt = bid & 1, st = (bid >> 1) & 31, kvh = (bid >> 6) & 3, b = bid >> 8;
  __shared__ __align__(16) __bf16 tile[64][72];
  int t = threadIdx.x;
#pragma unroll
  for (int i = 0; i < 2; ++i) {
    int c = (i << 8) + t;
    int sr = c >> 3, cb = (c & 7) << 3;
    bf16x8 v = *(const bf16x8*)(V + (size_t)(b * S_LEN + st * 64 + sr) * 512 +
                                kvh * HDK + dt * 64 + cb);
    *(bf16x8*)(&tile[sr][cb]) = v;
  }
  __syncthreads();
#pragma unroll
  for (int i = 0; i < 2; ++i) {
    int c = (i << 8) + t;
    int dr = c >> 3, sb = (c & 7) << 3;
    bf16x8 o;
#pragma unroll
    for (int j = 0; j < 8; ++j) o[j] = tile[sb + j][dr];
    *(bf16x8*)(Vt + (size_t)((b * NKVH + kvh) * HDK + dt * 64 + dr) * S_LEN +
               st * 64 + sb) = o;
  }
}

// ---------------- causal GQA flash attention (2-phase double-buffered) ----------------
// Q:(B*S,2048) K:(B*S,512) Vt:((b*4+kvh)*128, S) -> Ctx:(B*S,2048), all bf16
__global__ __launch_bounds__(256) void attn(const __bf16* __restrict__ Q,
                                            const __bf16* __restrict__ Kx,
                                            const __bf16* __restrict__ Vt,
                                            __bf16* __restrict__ Ctx) {
  int bid = blockIdx.x;
  int qt = 31 - (bid & 31);  // longest blocks first
  int h = (bid >> 5) & 15;
  int b = bid >> 9;
  int kvh = h >> 2;
  int q0 = qt << 6;
  int t = threadIdx.x, lane = t & 63, w = t >> 6;

  __shared__ __align__(16) uint8_t Ks[2][16384];  // [64][128] bf16, swizzled
  __shared__ __align__(16) uint8_t Vs[2][16384];  // [128][64] bf16 (d-major), swizzled
  __shared__ __align__(16) __bf16 Ps[4][16][72];  // per-wave P, padded

  const __bf16* kbase = Kx + (size_t)b * S_LEN * 512 + kvh * HDK;
  const __bf16* vbase = Vt + (size_t)(b * NKVH + kvh) * HDK * S_LEN;

  auto stage = [&](int kt, int bufi) {
#pragma unroll
    for (int i = 0; i < 4; ++i) {
      int c = (i << 8) + t;
      int krow = c >> 4;
      int kcolb = ((c & 15) << 4) ^ ((krow & 7) << 4);
      async16((const uint8_t*)(kbase + (size_t)((kt << 6) + krow) * 512) + kcolb,
              Ks[bufi] + c * 16);
      int vrow = c >> 3;
      int vcolb = ((c & 7) << 4) ^ ((vrow & 7) << 4);
      async16((const uint8_t*)(vbase + (size_t)vrow * S_LEN + (kt << 6)) + vcolb,
              Vs[bufi] + c * 16);
    }
  };

  // prologue: stage tile 0; Q -> regs directly from global (one-time)
  stage(0, 0);
  bf16x8 qf[4];
  {
    const __bf16* qbase = Q + (size_t)(b * S_LEN + q0 + w * 16 + (lane & 15)) * DMODEL +
                          h * HDK + ((lane >> 4) << 3);
#pragma unroll
    for (int dc = 0; dc < 4; ++dc) qf[dc] = *(const bf16x8*)(qbase + dc * 32);
  }
  __syncthreads();  // drains vmcnt for tile 0

  const float NEG = -3.0e38f;
  const float SC = 0.08838834764831845f;  // 1/sqrt(128)
  float m_run[4] = {NEG, NEG, NEG, NEG};
  float l_run[4] = {0.f, 0.f, 0.f, 0.f};
  f32x4 acc_o[8] = {};

  for (int kt = 0; kt <= qt; ++kt) {
    int cur = kt & 1;
    if (kt < qt) stage(kt + 1, cur ^ 1);  // overlap next-tile load with compute

    const uint8_t* ks = Ks[cur];
    const uint8_t* vs = Vs[cur];

    // S = Q K^T  (16q x 64k per wave)
    f32x4 sc[4] = {};
    __builtin_amdgcn_s_setprio(1);
#pragma unroll
    for (int kf = 0; kf < 4; ++kf)
#pragma unroll
      for (int dc = 0; dc < 4; ++dc) {
        int row = kf * 16 + (lane & 15);
        int colb = ((dc << 6) + ((lane >> 4) << 4)) ^ ((row & 7) << 4);
        bf16x8 kfr = *(const bf16x8*)(ks + row * 256 + colb);
        sc[kf] = mfma16(qf[dc], kfr, sc[kf]);
      }
    __builtin_amdgcn_s_setprio(0);

    if (kt == qt) {
#pragma unroll
      for (int kf = 0; kf < 4; ++kf)
#pragma unroll
        for (int j = 0; j < 4; ++j) {
          int key = kf * 16 + (lane & 15);
          int qq = w * 16 + ((lane >> 4) << 2) + j;
          sc[kf][j] = (key <= qq) ? sc[kf][j] * SC : NEG;
        }
    } else {
#pragma unroll
      for (int kf = 0; kf < 4; ++kf)
#pragma unroll
        for (int j = 0; j < 4; ++j) sc[kf][j] *= SC;
    }

    float mx[4];
#pragma unroll
    for (int j = 0; j < 4; ++j)
      mx[j] = fmaxf(fmaxf(sc[0][j], sc[1][j]), fmaxf(sc[2][j], sc[3][j]));
#pragma unroll
    for (int off = 1; off < 16; off <<= 1)
#pragma unroll
      for (int j = 0; j < 4; ++j) mx[j] = fmaxf(mx[j], __shfl_xor(mx[j], off, 64));

    // defer-max (T13): only rescale when the running max actually grows by >8
    float grow = fmaxf(fmaxf(mx[0] - m_run[0], mx[1] - m_run[1]),
                       fmaxf(mx[2] - m_run[2], mx[3] - m_run[3]));
    if (__any(grow > 8.f)) {
      float al[4];
#pragma unroll
      for (int j = 0; j < 4; ++j) {
        float mn = fmaxf(m_run[j], mx[j]);
        al[j] = __expf(m_run[j] - mn);
        m_run[j] = mn;
        l_run[j] *= al[j];
      }
#pragma unroll
      for (int nf = 0; nf < 8; ++nf)
#pragma unroll
        for (int j = 0; j < 4; ++j) acc_o[nf][j] *= al[j];
    }

    float rs[4] = {0.f, 0.f, 0.f, 0.f};
#pragma unroll
    for (int kf = 0; kf < 4; ++kf)
#pragma unroll
      for (int j = 0; j < 4; ++j) {
        float p = __expf(sc[kf][j] - m_run[j]);
        sc[kf][j] = p;
        rs[j] += p;
      }
#pragma unroll
    for (int off = 1; off < 16; off <<= 1)
#pragma unroll
      for (int j = 0; j < 4; ++j) rs[j] += __shfl_xor(rs[j], off, 64);
#pragma unroll
    for (int j = 0; j < 4; ++j) l_run[j] += rs[j];

    // P -> LDS (C-layout scatter), read back as MFMA A-frags
#pragma unroll
    for (int kf = 0; kf < 4; ++kf)
#pragma unroll
      for (int j = 0; j < 4; ++j)
        Ps[w][((lane >> 4) << 2) + j][kf * 16 + (lane & 15)] = (__bf16)sc[kf][j];
    bf16x8 pa[2];
#pragma unroll
    for (int kc = 0; kc < 2; ++kc)
      pa[kc] = *(const bf16x8*)(&Ps[w][lane & 15][kc * 32 + ((lane >> 4) << 3)]);

    // O += P V
    __builtin_amdgcn_s_setprio(1);
#pragma unroll
    for (int nf = 0; nf < 8; ++nf)
#pragma unroll
      for (int kc = 0; kc < 2; ++kc) {
        int row = nf * 16 + (lane & 15);
        int colb = ((kc << 6) + ((lane >> 4) << 4)) ^ ((row & 7) << 4);
        bf16x8 vfr = *(const bf16x8*)(vs + row * 128 + colb);
        acc_o[nf] = mfma16(pa[kc], vfr, acc_o[nf]);
      }
    __builtin_amdgcn_s_setprio(0);

    __syncthreads();  // single barrier: drains next-tile stage, releases cur buf
  }

  float inv[4];
#pragma unroll
  for (int j = 0; j < 4; ++j) inv[j] = 1.f / l_run[j];
#pragma unroll
  for (int nf = 0; nf < 8; ++nf)
#pragma unroll
    for (int j = 0; j < 4; ++j) {
      size_t idx = (size_t)(b * S_LEN + q0 + w * 16 + ((lane >> 4) << 2) + j) * DMODEL +
                   h * HDK + nf * 16 + (lane & 15);
      Ctx[idx] = (__bf16)(acc_o[nf][j] * inv[j]);
    }
}

// ---------------- launch ----------------
extern "C" void kernel_launch(void* const* d_in, const int* in_sizes, int n_in,
                              void* d_out, int out_size, void* d_ws, size_t ws_size,
                              hipStream_t stream) {
  const float* x  = (const float*)d_in[0];
  const float* Wq = (const float*)d_in[1];
  const float* Wk = (const float*)d_in[2];
  const float* Wv = (const float*)d_in[3];
  const float* Wo = (const float*)d_in[4];
  float* out = (float*)d_out;

  const size_t MB = 1024 * 1024;
  uint8_t* ws = (uint8_t*)d_ws;
  __bf16* xb  = (__bf16*)(ws + 0 * MB);   // 16 MB  (4096 x 2048)
  __bf16* Wqb = (__bf16*)(ws + 16 * MB);  //  8 MB  (2048 x 2048)
  __bf16* Wkb = (__bf16*)(ws + 24 * MB);  //  2 MB  (512 x 2048)
  __bf16* Wvb = (__bf16*)(ws + 26 * MB);  //  2 MB
  __bf16* Wob = (__bf16*)(ws + 28 * MB);  //  8 MB
  __bf16* Qb  = (__bf16*)(ws + 36 * MB);  // 16 MB  (4096 x 2048)
  __bf16* Kb  = (__bf16*)(ws + 52 * MB);  //  4 MB  (4096 x 512)
  __bf16* Vb  = (__bf16*)(ws + 56 * MB);  //  4 MB
  __bf16* Vtb = (__bf16*)(ws + 60 * MB);  //  4 MB  (1024 x 2048)
  __bf16* Ctx = (__bf16*)(ws + 64 * MB);  // 16 MB  (4096 x 2048)

  cvt_bf16<<<8388608 / 2048, 256, 0, stream>>>(x, xb, 8388608);
  cvt_bf16<<<4194304 / 2048, 256, 0, stream>>>(Wq, Wqb, 4194304);
  cvt_bf16<<<1048576 / 2048, 256, 0, stream>>>(Wk, Wkb, 1048576);
  cvt_bf16<<<1048576 / 2048, 256, 0, stream>>>(Wv, Wvb, 1048576);
  cvt_bf16<<<4194304 / 2048, 256, 0, stream>>>(Wo, Wob, 4194304);

  // Q projection: (4096x2048) x (2048x2048)^T
  gemm_bt<false><<<(4096 / 128) * (2048 / 128), 256, 0, stream>>>(
      xb, Wqb, Wqb, (void*)Qb, (void*)Qb, 4096, 2048, 2048, 2048);
  // K|V projections fused: N = 512+512
  gemm_bt<false><<<(4096 / 128) * (1024 / 128), 256, 0, stream>>>(
      xb, Wkb, Wvb, (void*)Kb, (void*)Vb, 4096, 1024, 512, 2048);

  transpose_v<<<512, 256, 0, stream>>>(Vb, Vtb);

  attn<<<2 * 16 * 32, 256, 0, stream>>>(Qb, Kb, Vtb, Ctx);

  // output projection: (4096x2048) x (2048x2048)^T -> fp32
  gemm_bt<true><<<(4096 / 128) * (2048 / 128), 256, 0, stream>>>(
      Ctx, Wob, Wob, (void*)out, (void*)out, 4096, 2048, 2048, 2048);
}

// Round 3
// 233.223 us; speedup vs baseline: 1.3539x; 1.3511x over previous
//
#include <hip/hip_runtime.h>
#include <stdint.h>

#define S_LEN 2048
#define DMODEL 2048
#define NQH 16
#define NKVH 4
#define HDK 128

typedef __bf16 bf16x8 __attribute__((ext_vector_type(8)));
typedef float f32x4 __attribute__((ext_vector_type(4)));
typedef float f32x16 __attribute__((ext_vector_type(16)));

__device__ __forceinline__ void async16(const void* g, void* l) {
  __builtin_amdgcn_global_load_lds((const __attribute__((address_space(1))) void*)g,
                                   (__attribute__((address_space(3))) void*)l,
                                   16, 0, 0);
}

__device__ __forceinline__ f32x4 mfma16(bf16x8 a, bf16x8 b, f32x4 c) {
  return __builtin_amdgcn_mfma_f32_16x16x32_bf16(a, b, c, 0, 0, 0);
}
__device__ __forceinline__ f32x16 mfma32(bf16x8 a, bf16x8 b, f32x16 c) {
  return __builtin_amdgcn_mfma_f32_32x32x16_bf16(a, b, c, 0, 0, 0);
}
__device__ __forceinline__ uint32_t pkbf16(float lo, float hi) {
  uint32_t r;
  asm("v_cvt_pk_bf16_f32 %0, %1, %2" : "=v"(r) : "v"(lo), "v"(hi));
  return r;
}

// ---------------- fp32 -> bf16 conversion ----------------
__global__ __launch_bounds__(256) void cvt_bf16(const float* __restrict__ in,
                                                __bf16* __restrict__ out, int n) {
  int i = (blockIdx.x * 256 + threadIdx.x) * 8;
  if (i >= n) return;
  const float4* p = (const float4*)(in + i);
  float4 a = p[0], b = p[1];
  bf16x8 o;
  o[0] = (__bf16)a.x; o[1] = (__bf16)a.y; o[2] = (__bf16)a.z; o[3] = (__bf16)a.w;
  o[4] = (__bf16)b.x; o[5] = (__bf16)b.y; o[6] = (__bf16)b.z; o[7] = (__bf16)b.w;
  *(bf16x8*)(out + i) = o;
}

// ---------------- GEMM: C[m,n] = sum_k A[m,k]*B[n,k] ----------------
template <bool F32OUT>
__global__ __launch_bounds__(256) void gemm_bt(const __bf16* __restrict__ A,
                                               const __bf16* __restrict__ Ba,
                                               const __bf16* __restrict__ Bb,
                                               void* __restrict__ Ca,
                                               void* __restrict__ Cb,
                                               int M, int Ntot, int Nsplit, int K) {
  int nbn = Ntot >> 7;
  int bx = blockIdx.x;
  int m0 = (bx / nbn) << 7;
  int n0g = (bx % nbn) << 7;
  const __bf16* B;
  void* C;
  int n0, Nc;
  if (n0g < Nsplit) { B = Ba; C = Ca; n0 = n0g; Nc = Nsplit; }
  else              { B = Bb; C = Cb; n0 = n0g - Nsplit; Nc = Ntot - Nsplit; }

  __shared__ __align__(16) uint8_t As[16384]; // [128][64] bf16, XOR-swizzled
  __shared__ __align__(16) uint8_t Bs[16384];

  int t = threadIdx.x, lane = t & 63, w = t >> 6;
  int wr = w >> 1, wc = w & 1;
  f32x4 acc[4][4] = {};

  for (int k0 = 0; k0 < K; k0 += 64) {
#pragma unroll
    for (int i = 0; i < 4; ++i) {
      int c = (i << 8) + t;
      int row = c >> 3;
      int colb = ((c & 7) << 4) ^ ((row & 7) << 4);
      async16((const uint8_t*)(A + (size_t)(m0 + row) * K + k0) + colb, As + c * 16);
      async16((const uint8_t*)(B + (size_t)(n0 + row) * K + k0) + colb, Bs + c * 16);
    }
    __syncthreads();
#pragma unroll
    for (int ks = 0; ks < 2; ++ks) {
      bf16x8 af[4], bfr[4];
#pragma unroll
      for (int m = 0; m < 4; ++m) {
        int row = wr * 64 + m * 16 + (lane & 15);
        int colb = ((ks << 6) + ((lane >> 4) << 4)) ^ ((row & 7) << 4);
        af[m] = *(const bf16x8*)(As + row * 128 + colb);
      }
#pragma unroll
      for (int n = 0; n < 4; ++n) {
        int row = wc * 64 + n * 16 + (lane & 15);
        int colb = ((ks << 6) + ((lane >> 4) << 4)) ^ ((row & 7) << 4);
        bfr[n] = *(const bf16x8*)(Bs + row * 128 + colb);
      }
      __builtin_amdgcn_s_setprio(1);
#pragma unroll
      for (int m = 0; m < 4; ++m)
#pragma unroll
        for (int n = 0; n < 4; ++n)
          acc[m][n] = mfma16(af[m], bfr[n], acc[m][n]);
      __builtin_amdgcn_s_setprio(0);
    }
    __syncthreads();
  }
#pragma unroll
  for (int m = 0; m < 4; ++m)
#pragma unroll
    for (int n = 0; n < 4; ++n)
#pragma unroll
      for (int j = 0; j < 4; ++j) {
        int mg = m0 + wr * 64 + m * 16 + ((lane >> 4) << 2) + j;
        int ng = n0 + wc * 64 + n * 16 + (lane & 15);
        float v = acc[m][n][j];
        if (F32OUT) ((float*)C)[(size_t)mg * Nc + ng] = v;
        else        ((__bf16*)C)[(size_t)mg * Nc + ng] = (__bf16)v;
      }
}

// ---------------- V transpose: (B*S, 512) -> Vt[(b*4+kvh)*128 + d][s] ----------------
__global__ __launch_bounds__(256) void transpose_v(const __bf16* __restrict__ V,
                                                   __bf16* __restrict__ Vt) {
  int bid = blockIdx.x;
  int dt = bid & 1, st = (bid >> 1) & 31, kvh = (bid >> 6) & 3, b = bid >> 8;
  __shared__ __align__(16) __bf16 tile[64][72];
  int t = threadIdx.x;
#pragma unroll
  for (int i = 0; i < 2; ++i) {
    int c = (i << 8) + t;
    int sr = c >> 3, cb = (c & 7) << 3;
    bf16x8 v = *(const bf16x8*)(V + (size_t)(b * S_LEN + st * 64 + sr) * 512 +
                                kvh * HDK + dt * 64 + cb);
    *(bf16x8*)(&tile[sr][cb]) = v;
  }
  __syncthreads();
#pragma unroll
  for (int i = 0; i < 2; ++i) {
    int c = (i << 8) + t;
    int dr = c >> 3, sb = (c & 7) << 3;
    bf16x8 o;
#pragma unroll
    for (int j = 0; j < 8; ++j) o[j] = tile[sb + j][dr];
    *(bf16x8*)(Vt + (size_t)((b * NKVH + kvh) * HDK + dt * 64 + dr) * S_LEN +
               st * 64 + sb) = o;
  }
}

// ---------------- causal GQA flash attention, 32x32 swapped-QK^T ----------------
// 4 waves x 32 q-rows (QBLK=128), KVBLK=64, in-register softmax (lane owns q=lane&31).
__global__ __launch_bounds__(256, 2) void attn(const __bf16* __restrict__ Q,
                                               const __bf16* __restrict__ Kx,
                                               const __bf16* __restrict__ Vt,
                                               __bf16* __restrict__ Ctx) {
  int bid = blockIdx.x;
  int qt = 15 - (bid & 15);  // longest blocks first
  int h = (bid >> 4) & 15;
  int b = bid >> 8;
  int kvh = h >> 2;
  int q0 = qt << 7;
  int t = threadIdx.x, lane = t & 63, w = t >> 6;
  int qr = lane & 31;   // own q-row within wave
  int hi = lane >> 5;
  int qwb = q0 + (w << 5);

  __shared__ __align__(16) uint8_t Ks[2][16384];  // [64 key][128 d] bf16, swizzled
  __shared__ __align__(16) uint8_t Vs[2][16384];  // [128 d][64 key] bf16, swizzled

  const __bf16* kbase = Kx + (size_t)b * S_LEN * 512 + kvh * HDK;
  const __bf16* vbase = Vt + (size_t)(b * NKVH + kvh) * HDK * S_LEN;

  auto stage = [&](int kt, int bufi) {
#pragma unroll
    for (int i = 0; i < 4; ++i) {
      int c = (i << 8) + t;
      int krow = c >> 4;
      int kcolb = ((c & 15) << 4) ^ ((krow & 7) << 4);
      async16((const uint8_t*)(kbase + (size_t)((kt << 6) + krow) * 512) + kcolb,
              Ks[bufi] + c * 16);
      int vrow = c >> 3;
      int vcolb = ((c & 7) << 4) ^ ((vrow & 7) << 4);
      async16((const uint8_t*)(vbase + (size_t)vrow * S_LEN + (kt << 6)) + vcolb,
              Vs[bufi] + c * 16);
    }
  };

  int NT = (qt << 1) + 2;
  stage(0, 0);

  // Q fragments: lane holds Q[q = qwb+qr][d = dk*16 + hi*8 + j]
  bf16x8 qf[8];
  {
    const __bf16* qrow = Q + (size_t)(b * S_LEN + qwb + qr) * DMODEL + h * HDK + hi * 8;
#pragma unroll
    for (int dk = 0; dk < 8; ++dk) qf[dk] = *(const bf16x8*)(qrow + dk * 16);
  }
  __syncthreads();

  const float NEG = -3.0e38f;
  const float SC = 0.08838834764831845f;  // 1/sqrt(128)
  float m_run = NEG, l_run = 0.f;
  f32x16 acc[4] = {};  // O[q][d], 4 d-tiles of 32

  for (int kt = 0; kt < NT; ++kt) {
    int cur = kt & 1;
    if (kt + 1 < NT) stage(kt + 1, cur ^ 1);
    int k0 = kt << 6;
    if (k0 <= qwb + 31) {  // wave-uniform skip of fully-masked tiles
      const uint8_t* ks = Ks[cur];
      const uint8_t* vs = Vs[cur];

      // S^T = K Q^T : D[key][q], col=q=lane&31, row=(r&3)+8*(r>>2)+4*hi
      f32x16 st0 = {}, st1 = {};
      __builtin_amdgcn_s_setprio(1);
#pragma unroll
      for (int dk = 0; dk < 8; ++dk) {
        int cb = (dk << 5) + (hi << 4);
        int swz = (qr & 7) << 4;
        bf16x8 kf0 = *(const bf16x8*)(ks + qr * 256 + (cb ^ swz));
        st0 = mfma32(kf0, qf[dk], st0);
        bf16x8 kf1 = *(const bf16x8*)(ks + (32 + qr) * 256 + (cb ^ swz));
        st1 = mfma32(kf1, qf[dk], st1);
      }
      __builtin_amdgcn_s_setprio(0);

      // causal mask (diagonal-adjacent tiles only)
      if (k0 + 63 > qwb) {
#pragma unroll
        for (int r = 0; r < 16; ++r) {
          int kl = (r & 3) + ((r >> 2) << 3) + (hi << 2);
          st0[r] = (k0 + kl > qwb + qr) ? NEG : st0[r];
          st1[r] = (k0 + 32 + kl > qwb + qr) ? NEG : st1[r];
        }
      }

      // row max: in-register tree + one cross-half merge
      float mx = fmaxf(st0[0], st1[0]);
#pragma unroll
      for (int r = 1; r < 16; ++r) mx = fmaxf(mx, fmaxf(st0[r], st1[r]));
      mx = fmaxf(mx, __shfl_xor(mx, 32, 64));

      // defer-max: rescale only when max grows by >8/SC in raw score units
      if (__any(mx > m_run + 90.52f)) {
        float mn = fmaxf(m_run, mx);
        float al = __expf((m_run - mn) * SC);
        l_run *= al;
        m_run = mn;
#pragma unroll
        for (int i = 0; i < 16; ++i) {
          float alr = __shfl(al, (i & 3) + ((i >> 2) << 3) + (hi << 2), 64);
          acc[0][i] *= alr; acc[1][i] *= alr; acc[2][i] *= alr; acc[3][i] *= alr;
        }
      }

      float mSC = m_run * SC;
      float rs = 0.f;
      float p0[16], p1[16];
#pragma unroll
      for (int r = 0; r < 16; ++r) { p0[r] = __expf(fmaf(st0[r], SC, -mSC)); rs += p0[r]; }
#pragma unroll
      for (int r = 0; r < 16; ++r) { p1[r] = __expf(fmaf(st1[r], SC, -mSC)); rs += p1[r]; }
      rs += __shfl_xor(rs, 32, 64);
      l_run += rs;

      // pack P to bf16 and redistribute to PV A-frag layout
      // own half-runs: wd[g] = keys {8g+4hi .. 8g+4hi+3} of its k-half
      uint32_t wd0[4][2], wd1[4][2];
#pragma unroll
      for (int g = 0; g < 4; ++g) {
        wd0[g][0] = pkbf16(p0[4 * g + 0], p0[4 * g + 1]);
        wd0[g][1] = pkbf16(p0[4 * g + 2], p0[4 * g + 3]);
        wd1[g][0] = pkbf16(p1[4 * g + 0], p1[4 * g + 1]);
        wd1[g][1] = pkbf16(p1[4 * g + 2], p1[4 * g + 3]);
      }
      bf16x8 pa[4];
#define PEXCH(WD, IDX0, IDX1)                                                  \
      {                                                                        \
        uint32_t s0 = hi ? WD[0][0] : WD[1][0];                                \
        uint32_t s1 = hi ? WD[0][1] : WD[1][1];                                \
        uint32_t s2 = hi ? WD[2][0] : WD[3][0];                                \
        uint32_t s3 = hi ? WD[2][1] : WD[3][1];                                \
        uint32_t r0 = (uint32_t)__shfl_xor((int)s0, 32, 64);                   \
        uint32_t r1 = (uint32_t)__shfl_xor((int)s1, 32, 64);                   \
        uint32_t r2 = (uint32_t)__shfl_xor((int)s2, 32, 64);                   \
        uint32_t r3 = (uint32_t)__shfl_xor((int)s3, 32, 64);                   \
        union { bf16x8 v; uint32_t u[4]; } fa, fb;                             \
        fa.u[0] = hi ? r0 : WD[0][0];                                          \
        fa.u[1] = hi ? r1 : WD[0][1];                                          \
        fa.u[2] = hi ? WD[1][0] : r0;                                          \
        fa.u[3] = hi ? WD[1][1] : r1;                                          \
        fb.u[0] = hi ? r2 : WD[2][0];                                          \
        fb.u[1] = hi ? r3 : WD[2][1];                                          \
        fb.u[2] = hi ? WD[3][0] : r2;                                          \
        fb.u[3] = hi ? WD[3][1] : r3;                                          \
        pa[IDX0] = fa.v;                                                       \
        pa[IDX1] = fb.v;                                                       \
      }
      PEXCH(wd0, 0, 1)
      PEXCH(wd1, 2, 3)
#undef PEXCH

      // O += P V : A=pa (P[q][k]), B=V[k][d] from d-major Vt_lds
      __builtin_amdgcn_s_setprio(1);
#pragma unroll
      for (int dt = 0; dt < 4; ++dt) {
        int row = (dt << 5) + qr;
        int swz = (row & 7) << 4;
#pragma unroll
        for (int kc = 0; kc < 4; ++kc) {
          bf16x8 vf = *(const bf16x8*)(vs + row * 128 + (((kc << 5) + (hi << 4)) ^ swz));
          acc[dt] = mfma32(pa[kc], vf, acc[dt]);
        }
      }
      __builtin_amdgcn_s_setprio(0);
    }
    __syncthreads();
  }

  // epilogue: normalize by per-row l, write out
#pragma unroll
  for (int i = 0; i < 16; ++i) {
    int rm = (i & 3) + ((i >> 2) << 3) + (hi << 2);
    float lr = __shfl(l_run, rm, 64);
    float inv = 1.0f / lr;
    size_t rowoff = (size_t)(b * S_LEN + qwb + rm) * DMODEL + h * HDK + qr;
#pragma unroll
    for (int dt = 0; dt < 4; ++dt)
      Ctx[rowoff + (dt << 5)] = (__bf16)(acc[dt][i] * inv);
  }
}

// ---------------- launch ----------------
extern "C" void kernel_launch(void* const* d_in, const int* in_sizes, int n_in,
                              void* d_out, int out_size, void* d_ws, size_t ws_size,
                              hipStream_t stream) {
  const float* x  = (const float*)d_in[0];
  const float* Wq = (const float*)d_in[1];
  const float* Wk = (const float*)d_in[2];
  const float* Wv = (const float*)d_in[3];
  const float* Wo = (const float*)d_in[4];
  float* out = (float*)d_out;

  const size_t MB = 1024 * 1024;
  uint8_t* ws = (uint8_t*)d_ws;
  __bf16* xb  = (__bf16*)(ws + 0 * MB);   // 16 MB  (4096 x 2048)
  __bf16* Wqb = (__bf16*)(ws + 16 * MB);  //  8 MB  (2048 x 2048)
  __bf16* Wkb = (__bf16*)(ws + 24 * MB);  //  2 MB  (512 x 2048)
  __bf16* Wvb = (__bf16*)(ws + 26 * MB);  //  2 MB
  __bf16* Wob = (__bf16*)(ws + 28 * MB);  //  8 MB
  __bf16* Qb  = (__bf16*)(ws + 36 * MB);  // 16 MB  (4096 x 2048)
  __bf16* Kb  = (__bf16*)(ws + 52 * MB);  //  4 MB  (4096 x 512)
  __bf16* Vb  = (__bf16*)(ws + 56 * MB);  //  4 MB
  __bf16* Vtb = (__bf16*)(ws + 60 * MB);  //  4 MB  (1024 x 2048)
  __bf16* Ctx = (__bf16*)(ws + 64 * MB);  // 16 MB  (4096 x 2048)

  cvt_bf16<<<8388608 / 2048, 256, 0, stream>>>(x, xb, 8388608);
  cvt_bf16<<<4194304 / 2048, 256, 0, stream>>>(Wq, Wqb, 4194304);
  cvt_bf16<<<1048576 / 2048, 256, 0, stream>>>(Wk, Wkb, 1048576);
  cvt_bf16<<<1048576 / 2048, 256, 0, stream>>>(Wv, Wvb, 1048576);
  cvt_bf16<<<4194304 / 2048, 256, 0, stream>>>(Wo, Wob, 4194304);

  // Q projection: (4096x2048) x (2048x2048)^T
  gemm_bt<false><<<(4096 / 128) * (2048 / 128), 256, 0, stream>>>(
      xb, Wqb, Wqb, (void*)Qb, (void*)Qb, 4096, 2048, 2048, 2048);
  // K|V projections fused: N = 512+512
  gemm_bt<false><<<(4096 / 128) * (1024 / 128), 256, 0, stream>>>(
      xb, Wkb, Wvb, (void*)Kb, (void*)Vb, 4096, 1024, 512, 2048);

  transpose_v<<<512, 256, 0, stream>>>(Vb, Vtb);

  attn<<<2 * 16 * 16, 256, 0, stream>>>(Qb, Kb, Vtb, Ctx);

  // output projection: (4096x2048) x (2048x2048)^T -> fp32
  gemm_bt<true><<<(4096 / 128) * (2048 / 128), 256, 0, stream>>>(
      Ctx, Wob, Wob, (void*)out, (void*)out, 4096, 2048, 2048, 2048);
}

// Round 5
// 200.093 us; speedup vs baseline: 1.5781x; 1.1656x over previous
//
#include <hip/hip_runtime.h>
#include <stdint.h>

#define S_LEN 2048
#define DMODEL 2048
#define NQH 16
#define NKVH 4
#define HDK 128

typedef __bf16 bf16x8 __attribute__((ext_vector_type(8)));
typedef float f32x4 __attribute__((ext_vector_type(4)));
typedef float f32x16 __attribute__((ext_vector_type(16)));

__device__ __forceinline__ void async16(const void* g, void* l) {
  __builtin_amdgcn_global_load_lds((const __attribute__((address_space(1))) void*)g,
                                   (__attribute__((address_space(3))) void*)l,
                                   16, 0, 0);
}

__device__ __forceinline__ f32x4 mfma16(bf16x8 a, bf16x8 b, f32x4 c) {
  return __builtin_amdgcn_mfma_f32_16x16x32_bf16(a, b, c, 0, 0, 0);
}
__device__ __forceinline__ f32x16 mfma32(bf16x8 a, bf16x8 b, f32x16 c) {
  return __builtin_amdgcn_mfma_f32_32x32x16_bf16(a, b, c, 0, 0, 0);
}
__device__ __forceinline__ uint32_t pkbf16(float lo, float hi) {
  uint32_t r;
  asm("v_cvt_pk_bf16_f32 %0, %1, %2" : "=v"(r) : "v"(lo), "v"(hi));
  return r;
}

// ---------------- fused fp32 -> bf16 conversion (all 5 tensors) ----------------
__global__ __launch_bounds__(256) void cvt_all(
    const float* __restrict__ i0, const float* __restrict__ i1,
    const float* __restrict__ i2, const float* __restrict__ i3,
    const float* __restrict__ i4, __bf16* __restrict__ o0,
    __bf16* __restrict__ o1, __bf16* __restrict__ o2, __bf16* __restrict__ o3,
    __bf16* __restrict__ o4) {
  int v = blockIdx.x * 256 + threadIdx.x;  // vec8 index; total 2359296
  const float* in;
  __bf16* out;
  int base;
  if (v < 1048576)      { in = i0; out = o0; base = 0; }
  else if (v < 1572864) { in = i1; out = o1; base = 1048576; }
  else if (v < 1703936) { in = i2; out = o2; base = 1572864; }
  else if (v < 1835008) { in = i3; out = o3; base = 1703936; }
  else                  { in = i4; out = o4; base = 1835008; }
  int i = (v - base) * 8;
  const float4* p = (const float4*)(in + i);
  float4 a = p[0], b = p[1];
  bf16x8 o;
  o[0] = (__bf16)a.x; o[1] = (__bf16)a.y; o[2] = (__bf16)a.z; o[3] = (__bf16)a.w;
  o[4] = (__bf16)b.x; o[5] = (__bf16)b.y; o[6] = (__bf16)b.z; o[7] = (__bf16)b.w;
  *(bf16x8*)(out + i) = o;
}

// ---------------- GEMM: C[m,n] = sum_k A[m,k]*B[n,k], 3-way N-routed ----------------
template <bool F32OUT>
__global__ __launch_bounds__(256) void gemm_bt(const __bf16* __restrict__ A,
                                               const __bf16* __restrict__ B0,
                                               const __bf16* __restrict__ B1,
                                               const __bf16* __restrict__ B2,
                                               void* __restrict__ C0,
                                               void* __restrict__ C1,
                                               void* __restrict__ C2,
                                               int Ntot, int Ns1, int Ns2, int K) {
  int nbn = Ntot >> 7;
  int nwg = gridDim.x;
  int bid = blockIdx.x;
  int bx = (bid & 7) * (nwg >> 3) + (bid >> 3);  // XCD swizzle (nwg % 8 == 0)
  int m0 = (bx / nbn) << 7;
  int n0g = (bx % nbn) << 7;
  const __bf16* B;
  void* C;
  int n0, Nc;
  if (n0g < Ns1)      { B = B0; C = C0; n0 = n0g;       Nc = Ns1; }
  else if (n0g < Ns2) { B = B1; C = C1; n0 = n0g - Ns1; Nc = Ns2 - Ns1; }
  else                { B = B2; C = C2; n0 = n0g - Ns2; Nc = Ntot - Ns2; }

  __shared__ __align__(16) uint8_t As[16384]; // [128][64] bf16, XOR-swizzled
  __shared__ __align__(16) uint8_t Bs[16384];

  int t = threadIdx.x, lane = t & 63, w = t >> 6;
  int wr = w >> 1, wc = w & 1;
  f32x4 acc[4][4] = {};

  for (int k0 = 0; k0 < K; k0 += 64) {
#pragma unroll
    for (int i = 0; i < 4; ++i) {
      int c = (i << 8) + t;
      int row = c >> 3;
      int colb = ((c & 7) << 4) ^ ((row & 7) << 4);
      async16((const uint8_t*)(A + (size_t)(m0 + row) * K + k0) + colb, As + c * 16);
      async16((const uint8_t*)(B + (size_t)(n0 + row) * K + k0) + colb, Bs + c * 16);
    }
    __syncthreads();
#pragma unroll
    for (int ks = 0; ks < 2; ++ks) {
      bf16x8 af[4], bfr[4];
#pragma unroll
      for (int m = 0; m < 4; ++m) {
        int row = wr * 64 + m * 16 + (lane & 15);
        int colb = ((ks << 6) + ((lane >> 4) << 4)) ^ ((row & 7) << 4);
        af[m] = *(const bf16x8*)(As + row * 128 + colb);
      }
#pragma unroll
      for (int n = 0; n < 4; ++n) {
        int row = wc * 64 + n * 16 + (lane & 15);
        int colb = ((ks << 6) + ((lane >> 4) << 4)) ^ ((row & 7) << 4);
        bfr[n] = *(const bf16x8*)(Bs + row * 128 + colb);
      }
      __builtin_amdgcn_s_setprio(1);
#pragma unroll
      for (int m = 0; m < 4; ++m)
#pragma unroll
        for (int n = 0; n < 4; ++n)
          acc[m][n] = mfma16(af[m], bfr[n], acc[m][n]);
      __builtin_amdgcn_s_setprio(0);
    }
    __syncthreads();
  }
#pragma unroll
  for (int m = 0; m < 4; ++m)
#pragma unroll
    for (int n = 0; n < 4; ++n)
#pragma unroll
      for (int j = 0; j < 4; ++j) {
        int mg = m0 + wr * 64 + m * 16 + ((lane >> 4) << 2) + j;
        int ng = n0 + wc * 64 + n * 16 + (lane & 15);
        float v = acc[m][n][j];
        if (F32OUT) ((float*)C)[(size_t)mg * Nc + ng] = v;
        else        ((__bf16*)C)[(size_t)mg * Nc + ng] = (__bf16)v;
      }
}

// ---------------- V transpose: (B*S, 512) -> Vt[(b*4+kvh)*128 + d][s] ----------------
__global__ __launch_bounds__(256) void transpose_v(const __bf16* __restrict__ V,
                                                   __bf16* __restrict__ Vt) {
  int bid = blockIdx.x;
  int dt = bid & 1, st = (bid >> 1) & 31, kvh = (bid >> 6) & 3, b = bid >> 8;
  __shared__ __align__(16) __bf16 tile[64][72];
  int t = threadIdx.x;
#pragma unroll
  for (int i = 0; i < 2; ++i) {
    int c = (i << 8) + t;
    int sr = c >> 3, cb = (c & 7) << 3;
    bf16x8 v = *(const bf16x8*)(V + (size_t)(b * S_LEN + st * 64 + sr) * 512 +
                                kvh * HDK + dt * 64 + cb);
    *(bf16x8*)(&tile[sr][cb]) = v;
  }
  __syncthreads();
#pragma unroll
  for (int i = 0; i < 2; ++i) {
    int c = (i << 8) + t;
    int dr = c >> 3, sb = (c & 7) << 3;
    bf16x8 o;
#pragma unroll
    for (int j = 0; j < 8; ++j) o[j] = tile[sb + j][dr];
    *(bf16x8*)(Vt + (size_t)((b * NKVH + kvh) * HDK + dt * 64 + dr) * S_LEN +
               st * 64 + sb) = o;
  }
}

// ---------------- causal GQA flash attention, 32x32 swapped-QK^T ----------------
// 4 waves x 32 q-rows (QBLK=128), KVBLK=64, in-register softmax (lane owns q=lane&31).
__global__ __launch_bounds__(256, 2) void attn(const __bf16* __restrict__ Q,
                                               const __bf16* __restrict__ Kx,
                                               const __bf16* __restrict__ Vt,
                                               __bf16* __restrict__ Ctx) {
  int bid0 = blockIdx.x;
  int bid = ((bid0 & 7) << 6) | (bid0 >> 3);  // XCD swizzle: 512 blocks, 64/XCD
  int qt = 15 - (bid & 15);
  int h = (bid >> 4) & 15;
  int b = bid >> 8;
  int kvh = h >> 2;
  int q0 = qt << 7;
  int t = threadIdx.x, lane = t & 63, w = t >> 6;
  int qr = lane & 31;   // own q-row within wave
  int hi = lane >> 5;
  int qwb = q0 + (w << 5);

  __shared__ __align__(16) uint8_t Ks[2][16384];  // [64 key][128 d] bf16, swizzled
  __shared__ __align__(16) uint8_t Vs[2][16384];  // [128 d][64 key] bf16, swizzled

  const __bf16* kbase = Kx + (size_t)b * S_LEN * 512 + kvh * HDK;
  const __bf16* vbase = Vt + (size_t)(b * NKVH + kvh) * HDK * S_LEN;

  auto stage = [&](int kt, int bufi) {
#pragma unroll
    for (int i = 0; i < 4; ++i) {
      int c = (i << 8) + t;
      int krow = c >> 4;
      int kcolb = ((c & 15) << 4) ^ ((krow & 7) << 4);
      async16((const uint8_t*)(kbase + (size_t)((kt << 6) + krow) * 512) + kcolb,
              Ks[bufi] + c * 16);
      int vrow = c >> 3;
      int vcolb = ((c & 7) << 4) ^ ((vrow & 7) << 4);
      async16((const uint8_t*)(vbase + (size_t)vrow * S_LEN + (kt << 6)) + vcolb,
              Vs[bufi] + c * 16);
    }
  };

  int NT = (qt << 1) + 2;
  stage(0, 0);

  // Q fragments: lane holds Q[q = qwb+qr][d = dk*16 + hi*8 + j]
  bf16x8 qf[8];
  {
    const __bf16* qrow = Q + (size_t)(b * S_LEN + qwb + qr) * DMODEL + h * HDK + hi * 8;
#pragma unroll
    for (int dk = 0; dk < 8; ++dk) qf[dk] = *(const bf16x8*)(qrow + dk * 16);
  }
  __syncthreads();

  const float NEG = -3.0e38f;
  const float SC = 0.08838834764831845f;  // 1/sqrt(128)
  float m_run = NEG, l_run = 0.f;
  f32x16 acc[4] = {};  // O[q][d], 4 d-tiles of 32

  for (int kt = 0; kt < NT; ++kt) {
    int cur = kt & 1;
    if (kt + 1 < NT) stage(kt + 1, cur ^ 1);
    int k0 = kt << 6;
    if (k0 <= qwb + 31) {  // wave-uniform skip of fully-masked tiles
      const uint8_t* ks = Ks[cur];
      const uint8_t* vs = Vs[cur];

      // S^T = K Q^T : D[key][q], col=q=lane&31, row=(r&3)+8*(r>>2)+4*hi
      f32x16 st0 = {}, st1 = {};
      __builtin_amdgcn_s_setprio(1);
#pragma unroll
      for (int dk = 0; dk < 8; ++dk) {
        int cb = (dk << 5) + (hi << 4);
        int swz = (qr & 7) << 4;
        bf16x8 kf0 = *(const bf16x8*)(ks + qr * 256 + (cb ^ swz));
        st0 = mfma32(kf0, qf[dk], st0);
        bf16x8 kf1 = *(const bf16x8*)(ks + (32 + qr) * 256 + (cb ^ swz));
        st1 = mfma32(kf1, qf[dk], st1);
      }
      __builtin_amdgcn_s_setprio(0);

      // causal mask (diagonal-adjacent tiles only)
      if (k0 + 63 > qwb) {
#pragma unroll
        for (int r = 0; r < 16; ++r) {
          int kl = (r & 3) + ((r >> 2) << 3) + (hi << 2);
          st0[r] = (k0 + kl > qwb + qr) ? NEG : st0[r];
          st1[r] = (k0 + 32 + kl > qwb + qr) ? NEG : st1[r];
        }
      }

      // row max: explicit binary tree (depth 5) + one cross-half merge
      float tm[16];
#pragma unroll
      for (int r = 0; r < 16; ++r) tm[r] = fmaxf(st0[r], st1[r]);
#pragma unroll
      for (int s = 8; s > 0; s >>= 1)
#pragma unroll
        for (int r = 0; r < s; ++r) tm[r] = fmaxf(tm[r], tm[r + s]);
      float mx = fmaxf(tm[0], __shfl_xor(tm[0], 32, 64));

      // defer-max: rescale only when max grows by >8/SC in raw score units
      if (__any(mx > m_run + 90.52f)) {
        float mn = fmaxf(m_run, mx);
        float al = __expf((m_run - mn) * SC);
        l_run *= al;
        m_run = mn;
#pragma unroll
        for (int i = 0; i < 16; ++i) {
          float alr = __shfl(al, (i & 3) + ((i >> 2) << 3) + (hi << 2), 64);
          acc[0][i] *= alr; acc[1][i] *= alr; acc[2][i] *= alr; acc[3][i] *= alr;
        }
      }

      float mSC = m_run * SC;
      float p0[16], p1[16];
#pragma unroll
      for (int r = 0; r < 16; ++r) p0[r] = __expf(fmaf(st0[r], SC, -mSC));
#pragma unroll
      for (int r = 0; r < 16; ++r) p1[r] = __expf(fmaf(st1[r], SC, -mSC));
      // row sum: binary tree + one cross-half merge
      float ts[16];
#pragma unroll
      for (int r = 0; r < 16; ++r) ts[r] = p0[r] + p1[r];
#pragma unroll
      for (int s = 8; s > 0; s >>= 1)
#pragma unroll
        for (int r = 0; r < s; ++r) ts[r] += ts[r + s];
      l_run += ts[0] + __shfl_xor(ts[0], 32, 64);

      // pack P to bf16 and redistribute to PV A-frag layout (shfl_xor + select)
      uint32_t wd0[4][2], wd1[4][2];
#pragma unroll
      for (int g = 0; g < 4; ++g) {
        wd0[g][0] = pkbf16(p0[4 * g + 0], p0[4 * g + 1]);
        wd0[g][1] = pkbf16(p0[4 * g + 2], p0[4 * g + 3]);
        wd1[g][0] = pkbf16(p1[4 * g + 0], p1[4 * g + 1]);
        wd1[g][1] = pkbf16(p1[4 * g + 2], p1[4 * g + 3]);
      }
      bf16x8 pa[4];
#define PEXCH(WD, IDX0, IDX1)                                                  \
      {                                                                        \
        uint32_t s0 = hi ? WD[0][0] : WD[1][0];                                \
        uint32_t s1 = hi ? WD[0][1] : WD[1][1];                                \
        uint32_t s2 = hi ? WD[2][0] : WD[3][0];                                \
        uint32_t s3 = hi ? WD[2][1] : WD[3][1];                                \
        uint32_t r0 = (uint32_t)__shfl_xor((int)s0, 32, 64);                   \
        uint32_t r1 = (uint32_t)__shfl_xor((int)s1, 32, 64);                   \
        uint32_t r2 = (uint32_t)__shfl_xor((int)s2, 32, 64);                   \
        uint32_t r3 = (uint32_t)__shfl_xor((int)s3, 32, 64);                   \
        union { bf16x8 v; uint32_t u[4]; } fa, fb;                             \
        fa.u[0] = hi ? r0 : WD[0][0];                                          \
        fa.u[1] = hi ? r1 : WD[0][1];                                          \
        fa.u[2] = hi ? WD[1][0] : r0;                                          \
        fa.u[3] = hi ? WD[1][1] : r1;                                          \
        fb.u[0] = hi ? r2 : WD[2][0];                                          \
        fb.u[1] = hi ? r3 : WD[2][1];                                          \
        fb.u[2] = hi ? WD[3][0] : r2;                                          \
        fb.u[3] = hi ? WD[3][1] : r3;                                          \
        pa[IDX0] = fa.v;                                                       \
        pa[IDX1] = fb.v;                                                       \
      }
      PEXCH(wd0, 0, 1)
      PEXCH(wd1, 2, 3)
#undef PEXCH

      // O += P V : A=pa (P[q][k]), B=V[k][d] from d-major Vt_lds
      __builtin_amdgcn_s_setprio(1);
#pragma unroll
      for (int dt = 0; dt < 4; ++dt) {
        int row = (dt << 5) + qr;
        int swz = (row & 7) << 4;
#pragma unroll
        for (int kc = 0; kc < 4; ++kc) {
          bf16x8 vf = *(const bf16x8*)(vs + row * 128 + (((kc << 5) + (hi << 4)) ^ swz));
          acc[dt] = mfma32(pa[kc], vf, acc[dt]);
        }
      }
      __builtin_amdgcn_s_setprio(0);
    }
    __syncthreads();
  }

  // epilogue: normalize by per-row l, write out
#pragma unroll
  for (int i = 0; i < 16; ++i) {
    int rm = (i & 3) + ((i >> 2) << 3) + (hi << 2);
    float lr = __shfl(l_run, rm, 64);
    float inv = 1.0f / lr;
    size_t rowoff = (size_t)(b * S_LEN + qwb + rm) * DMODEL + h * HDK + qr;
#pragma unroll
    for (int dt = 0; dt < 4; ++dt)
      Ctx[rowoff + (dt << 5)] = (__bf16)(acc[dt][i] * inv);
  }
}

// ---------------- launch ----------------
extern "C" void kernel_launch(void* const* d_in, const int* in_sizes, int n_in,
                              void* d_out, int out_size, void* d_ws, size_t ws_size,
                              hipStream_t stream) {
  const float* x  = (const float*)d_in[0];
  const float* Wq = (const float*)d_in[1];
  const float* Wk = (const float*)d_in[2];
  const float* Wv = (const float*)d_in[3];
  const float* Wo = (const float*)d_in[4];
  float* out = (float*)d_out;

  const size_t MB = 1024 * 1024;
  uint8_t* ws = (uint8_t*)d_ws;
  __bf16* xb  = (__bf16*)(ws + 0 * MB);   // 16 MB  (4096 x 2048)
  __bf16* Wqb = (__bf16*)(ws + 16 * MB);  //  8 MB  (2048 x 2048)
  __bf16* Wkb = (__bf16*)(ws + 24 * MB);  //  2 MB  (512 x 2048)
  __bf16* Wvb = (__bf16*)(ws + 26 * MB);  //  2 MB
  __bf16* Wob = (__bf16*)(ws + 28 * MB);  //  8 MB
  __bf16* Qb  = (__bf16*)(ws + 36 * MB);  // 16 MB  (4096 x 2048)
  __bf16* Kb  = (__bf16*)(ws + 52 * MB);  //  4 MB  (4096 x 512)
  __bf16* Vb  = (__bf16*)(ws + 56 * MB);  //  4 MB
  __bf16* Vtb = (__bf16*)(ws + 60 * MB);  //  4 MB  (1024 x 2048)
  __bf16* Ctx = (__bf16*)(ws + 64 * MB);  // 16 MB  (4096 x 2048)

  // fused conversion: 18.9M elems / 8 per thread / 256 per block = 9216 blocks
  cvt_all<<<9216, 256, 0, stream>>>(x, Wq, Wk, Wv, Wo, xb, Wqb, Wkb, Wvb, Wob);

  // fused QKV projection: (4096x2048) x [Wq;Wk;Wv]^T, N = 2048+512+512
  gemm_bt<false><<<(4096 / 128) * (3072 / 128), 256, 0, stream>>>(
      xb, Wqb, Wkb, Wvb, (void*)Qb, (void*)Kb, (void*)Vb, 3072, 2048, 2560, 2048);

  transpose_v<<<512, 256, 0, stream>>>(Vb, Vtb);

  attn<<<2 * 16 * 16, 256, 0, stream>>>(Qb, Kb, Vtb, Ctx);

  // output projection: (4096x2048) x (2048x2048)^T -> fp32
  gemm_bt<true><<<(4096 / 128) * (2048 / 128), 256, 0, stream>>>(
      Ctx, Wob, Wob, Wob, (void*)out, (void*)out, (void*)out, 2048, 2048, 2048, 2048);
}